// Round 16
// baseline (643.735 us; speedup 1.0000x reference)
//
#include <hip/hip_runtime.h>
#include <hip/hip_bf16.h>

#define NB 8
#define NS 1024
#define ND 1024
#define NH 16
#define NDK 64
#define NDFF 4096

typedef __bf16 bf16;
typedef __attribute__((ext_vector_type(8))) __bf16 bf16x8;
typedef __attribute__((ext_vector_type(4))) __bf16 bf16x4;
typedef __attribute__((ext_vector_type(4))) float f32x4;

__device__ __forceinline__ void gload16(const bf16* g, bf16* l) {
  __builtin_amdgcn_global_load_lds(
      (const __attribute__((address_space(1))) void*)g,
      (__attribute__((address_space(3))) void*)l, 16, 0, 0);
}

// ---- ONE-launch weight convert: 8 square (1024^2) + W1 (1024x4096) +
// W2 (4096x1024); 16384 tile-jobs of 32x32, job-decoded from blockIdx.x ----
struct WAll { const float* w[10]; };
__global__ void wconv_all(WAll wp, bf16* __restrict__ dst8,
                          bf16* __restrict__ W1T, bf16* __restrict__ W2T) {
  __shared__ float tile[32][33];
  const int j = blockIdx.x;
  const float* W;
  bf16* WT;
  int K, N, n0, k0;
  if (j < 8192) {
    int wi = j >> 10, r = j & 1023;
    W = wp.w[wi]; WT = dst8 + (size_t)wi * (1024 * 1024);
    K = 1024; N = 1024; n0 = (r & 31) * 32; k0 = (r >> 5) * 32;
  } else if (j < 12288) {
    int r = j - 8192;
    W = wp.w[8]; WT = W1T; K = 1024; N = 4096;
    n0 = (r & 127) * 32; k0 = (r >> 7) * 32;
  } else {
    int r = j - 12288;
    W = wp.w[9]; WT = W2T; K = 4096; N = 1024;
    n0 = (r & 31) * 32; k0 = (r >> 5) * 32;
  }
  int tx = threadIdx.x, ty = threadIdx.y;
#pragma unroll
  for (int i2 = 0; i2 < 4; ++i2) {
    int i = ty + i2 * 8;
    tile[i][tx] = W[(long)(k0 + i) * N + n0 + tx];
  }
  __syncthreads();
#pragma unroll
  for (int i2 = 0; i2 < 4; ++i2) {
    int i = ty + i2 * 8;
    WT[(long)(n0 + i) * K + k0 + tx] = (bf16)tile[tx][i];
  }
}

// ---- fused layernorm body ----
__device__ __forceinline__ void ln_body(
    const float* in, const float* gam, const float* bet, const float* pos,
    bf16* out_ln, bf16* out_lnpos, long row) {
  int t = threadIdx.x;  // 256
  float4 v = ((const float4*)(in + row * ND))[t];
  float s = v.x + v.y + v.z + v.w;
  float s2 = v.x * v.x + v.y * v.y + v.z * v.z + v.w * v.w;
#pragma unroll
  for (int m = 32; m >= 1; m >>= 1) {
    s += __shfl_xor(s, m);
    s2 += __shfl_xor(s2, m);
  }
  __shared__ float red[8];
  if ((t & 63) == 0) {
    red[t >> 6] = s;
    red[4 + (t >> 6)] = s2;
  }
  __syncthreads();
  float ts = red[0] + red[1] + red[2] + red[3];
  float ts2 = red[4] + red[5] + red[6] + red[7];
  float mu = ts * (1.0f / ND);
  float var = ts2 * (1.0f / ND) - mu * mu;
  float rstd = rsqrtf(var + 1e-5f);
  float4 g4 = ((const float4*)gam)[t];
  float4 b4 = ((const float4*)bet)[t];
  float o0 = (v.x - mu) * rstd * g4.x + b4.x;
  float o1 = (v.y - mu) * rstd * g4.y + b4.y;
  float o2 = (v.z - mu) * rstd * g4.z + b4.z;
  float o3 = (v.w - mu) * rstd * g4.w + b4.w;
  if (out_ln) {
    bf16x4 q;
    q[0] = (bf16)o0; q[1] = (bf16)o1; q[2] = (bf16)o2; q[3] = (bf16)o3;
    *(bf16x4*)(out_ln + row * ND + t * 4) = q;
  }
  if (out_lnpos) {
    float4 p4 = ((const float4*)(pos + row * ND))[t];
    bf16x4 q;
    q[0] = (bf16)(o0 + p4.x); q[1] = (bf16)(o1 + p4.y);
    q[2] = (bf16)(o2 + p4.z); q[3] = (bf16)(o3 + p4.w);
    *(bf16x4*)(out_lnpos + row * ND + t * 4) = q;
  }
}

__global__ void ln_fused(const float* __restrict__ in, const float* __restrict__ gam,
                         const float* __restrict__ bet, const float* __restrict__ pos,
                         bf16* __restrict__ out_ln, bf16* __restrict__ out_lnpos) {
  ln_body(in, gam, bet, pos, out_ln, out_lnpos, blockIdx.x);
}

__global__ void ln_fused2(
    const float* in0, const float* g0, const float* be0, const float* p0,
    bf16* oln0, bf16* olp0,
    const float* in1, const float* g1, const float* be1, const float* p1,
    bf16* oln1, bf16* olp1) {
  int sel = blockIdx.x >> 13;
  long row = blockIdx.x & 8191;
  if (sel == 0)
    ln_body(in0, g0, be0, p0, oln0, olp0, row);
  else
    ln_body(in1, g1, be1, p1, oln1, olp1, row);
}

// ==== GEMM v6 core: BM=BN=128, BK=32, 256 thr, 3-slot ring (48 KB ->
// 3 blocks/CU), stage t+2, counted vmcnt(4), 0-conflict swizzle.
// mode: 0 bf16; 1 f32 res+v; 2 bf16 swish; 3 bf16 VT-layout.
template <int MODE>
__device__ __forceinline__ void gemm_core(
    const bf16* A, const bf16* WT, const float* bias, const float* res,
    void* out, int N, int K, int mode_rt) {
  __shared__ bf16 SA[3][128 * 32];
  __shared__ bf16 SB[3][128 * 32];
  const int t = threadIdx.x;
  const int w = t >> 6, l = t & 63;
  const int wr = w >> 1, wc = w & 1;
  const int c = l & 15, g = l >> 4;
  const long row0 = (long)blockIdx.x * 128;
  const long col0 = (long)blockIdx.y * 128;
  const int NT = K >> 5;

  f32x4 acc[4][4];
#pragma unroll
  for (int m = 0; m < 4; ++m)
#pragma unroll
    for (int n = 0; n < 4; ++n) acc[m][n] = (f32x4){0.f, 0.f, 0.f, 0.f};

  const int srow = l >> 2;
  const int sslot = 8 * ((l & 3) ^ ((l >> 3) & 3));
  const bf16* Ag0 = A + (row0 + w * 16 + srow) * (long)K + sslot;
  const bf16* Ag1 = Ag0 + 64 * (long)K;
  const bf16* Bg0 = WT + (col0 + w * 16 + srow) * (long)K + sslot;
  const bf16* Bg1 = Bg0 + 64 * (long)K;
  bf16* const SAf = &SA[0][0];
  bf16* const SBf = &SB[0][0];

#define STAGEC(SL, KK)                                           \
  do {                                                           \
    gload16(Ag0 + (KK), SAf + (SL) * 4096 + (w * 16) * 32);      \
    gload16(Ag1 + (KK), SAf + (SL) * 4096 + (64 + w * 16) * 32); \
    gload16(Bg0 + (KK), SBf + (SL) * 4096 + (w * 16) * 32);      \
    gload16(Bg1 + (KK), SBf + (SL) * 4096 + (64 + w * 16) * 32); \
  } while (0)

  STAGEC(0, 0);
  STAGEC(1, 32);

  const int rsw = (g ^ ((c >> 1) & 3)) * 8;
  int aoff[4], boff[4];
#pragma unroll
  for (int m = 0; m < 4; ++m) aoff[m] = (wr * 64 + m * 16 + c) * 32 + rsw;
#pragma unroll
  for (int n = 0; n < 4; ++n) boff[n] = (wc * 64 + n * 16 + c) * 32 + rsw;

  asm volatile("s_waitcnt vmcnt(4)" ::: "memory");
  __builtin_amdgcn_s_barrier();

  int cb = 0, sb = 2, kst = 64;
  for (int tt = 0; tt < NT; ++tt) {
    const int ca = cb * 4096;
    bf16x8 af[4], bfr[4];
#pragma unroll
    for (int m = 0; m < 4; ++m) af[m] = *(const bf16x8*)(SAf + ca + aoff[m]);
#pragma unroll
    for (int n = 0; n < 4; ++n) bfr[n] = *(const bf16x8*)(SBf + ca + boff[n]);

    if (tt + 2 < NT) STAGEC(sb, kst);

    __builtin_amdgcn_s_barrier();
    asm volatile("s_waitcnt lgkmcnt(0)" ::: "memory");
    __builtin_amdgcn_sched_barrier(0);
    __builtin_amdgcn_s_setprio(1);
#pragma unroll
    for (int m = 0; m < 4; ++m)
#pragma unroll
      for (int n = 0; n < 4; ++n)
        acc[m][n] = __builtin_amdgcn_mfma_f32_16x16x32_bf16(af[m], bfr[n], acc[m][n], 0, 0, 0);
    __builtin_amdgcn_s_setprio(0);

    if (tt + 2 < NT) {
      asm volatile("s_waitcnt vmcnt(4)" ::: "memory");
    } else {
      asm volatile("s_waitcnt vmcnt(0)" ::: "memory");
    }
    __builtin_amdgcn_s_barrier();

    cb = (cb == 2) ? 0 : cb + 1;
    sb = (sb == 2) ? 0 : sb + 1;
    kst += 32;
  }
#undef STAGEC

  const int mode = (MODE >= 0) ? MODE : mode_rt;
  if (mode == 3) {
    bf16* VT = (bf16*)out;
#pragma unroll
    for (int n = 0; n < 4; ++n) {
      const long col = col0 + wc * 64 + n * 16 + c;
      const float bv = bias[col];
      const long h = col >> 6, dk = col & 63;
#pragma unroll
      for (int m = 0; m < 4; ++m) {
        const long rowb = row0 + wr * 64 + m * 16 + g * 4;
        const long b = rowb >> 10, s = rowb & 1023;
        bf16x4 ov;
#pragma unroll
        for (int r = 0; r < 4; ++r) ov[r] = (bf16)(acc[m][n][r] + bv);
        *(bf16x4*)(VT + (((b * NH + h) * NDK + dk) << 10) + s) = ov;
      }
    }
    return;
  }

#pragma unroll
  for (int n = 0; n < 4; ++n) {
    const long col = col0 + wc * 64 + n * 16 + c;
    const float bv = bias[col];
#pragma unroll
    for (int m = 0; m < 4; ++m) {
      const long rowb = row0 + wr * 64 + m * 16 + g * 4;
#pragma unroll
      for (int r = 0; r < 4; ++r) {
        float v = acc[m][n][r] + bv;
        const long idx = (rowb + r) * N + col;
        if (mode == 0) {
          ((bf16*)out)[idx] = (bf16)v;
        } else if (mode == 1) {
          ((float*)out)[idx] = res[idx] + v;
        } else {
          float sw = v / (1.f + __expf(-v));
          ((bf16*)out)[idx] = (bf16)sw;
        }
      }
    }
  }
}

template <int MODE>
__global__ __launch_bounds__(256) void gemm_bt(
    const bf16* __restrict__ A, const bf16* __restrict__ WT,
    const float* __restrict__ bias, const float* __restrict__ res,
    void* __restrict__ out, int M, int N, int K) {
  gemm_core<MODE>(A, WT, bias, res, out, N, K, 0);
}

struct GemmJob { const bf16* A; const bf16* WT; const float* bias; void* out; int mode; };
struct Jobs5 { GemmJob j[5]; };
__global__ __launch_bounds__(256) void gemm_multi(Jobs5 jobs) {
  const GemmJob& jb = jobs.j[blockIdx.z];
  gemm_core<-1>(jb.A, jb.WT, jb.bias, nullptr, jb.out, 1024, 1024, jb.mode);
}

// ---- GEMM v6-w8 (FFN1): BM=256, BN=128, BK=32, 512 thr, 3-slot ring ----
template <int MODE>
__global__ __launch_bounds__(512) void gemm_bt8(
    const bf16* __restrict__ A, const bf16* __restrict__ WT,
    const float* __restrict__ bias, const float* __restrict__ res,
    void* __restrict__ out, int M, int N, int K) {
  __shared__ bf16 SA[3][256 * 32];
  __shared__ bf16 SB[3][128 * 32];
  const int t = threadIdx.x;
  const int w = t >> 6, l = t & 63;
  const int wr = w >> 1, wc = w & 1;
  const int c = l & 15, g = l >> 4;
  const long row0 = (long)blockIdx.x * 256;
  const long col0 = (long)blockIdx.y * 128;
  const int NT = K >> 5;

  f32x4 acc[4][4];
#pragma unroll
  for (int m = 0; m < 4; ++m)
#pragma unroll
    for (int n = 0; n < 4; ++n) acc[m][n] = (f32x4){0.f, 0.f, 0.f, 0.f};

  const int srow = l >> 2;
  const int sslot = 8 * ((l & 3) ^ ((l >> 3) & 3));
  const bf16* Ag0 = A + (row0 + w * 16 + srow) * (long)K + sslot;
  const bf16* Ag1 = Ag0 + 128 * (long)K;
  const bf16* Bg0 = WT + (col0 + w * 16 + srow) * (long)K + sslot;
  bf16* const SAf = &SA[0][0];
  bf16* const SBf = &SB[0][0];

#define STAGE8(SL, KK)                                            \
  do {                                                            \
    gload16(Ag0 + (KK), SAf + (SL) * 8192 + (w * 16) * 32);       \
    gload16(Ag1 + (KK), SAf + (SL) * 8192 + (128 + w * 16) * 32); \
    gload16(Bg0 + (KK), SBf + (SL) * 4096 + (w * 16) * 32);       \
  } while (0)

  STAGE8(0, 0);
  STAGE8(1, 32);

  const int rsw = (g ^ ((c >> 1) & 3)) * 8;
  int aoff[4], boff[4];
#pragma unroll
  for (int m = 0; m < 4; ++m) aoff[m] = (wr * 64 + m * 16 + c) * 32 + rsw;
#pragma unroll
  for (int n = 0; n < 4; ++n) boff[n] = (wc * 64 + n * 16 + c) * 32 + rsw;

  asm volatile("s_waitcnt vmcnt(3)" ::: "memory");
  __builtin_amdgcn_s_barrier();

  int cb = 0, sb = 2, kst = 64;
  for (int tt = 0; tt < NT; ++tt) {
    bf16x8 af[4], bfr[4];
#pragma unroll
    for (int m = 0; m < 4; ++m) af[m] = *(const bf16x8*)(SAf + cb * 8192 + aoff[m]);
#pragma unroll
    for (int n = 0; n < 4; ++n) bfr[n] = *(const bf16x8*)(SBf + cb * 4096 + boff[n]);

    if (tt + 2 < NT) STAGE8(sb, kst);

    __builtin_amdgcn_s_barrier();
    asm volatile("s_waitcnt lgkmcnt(0)" ::: "memory");
    __builtin_amdgcn_sched_barrier(0);
    __builtin_amdgcn_s_setprio(1);
#pragma unroll
    for (int m = 0; m < 4; ++m)
#pragma unroll
      for (int n = 0; n < 4; ++n)
        acc[m][n] = __builtin_amdgcn_mfma_f32_16x16x32_bf16(af[m], bfr[n], acc[m][n], 0, 0, 0);
    __builtin_amdgcn_s_setprio(0);

    if (tt + 2 < NT) {
      asm volatile("s_waitcnt vmcnt(3)" ::: "memory");
    } else {
      asm volatile("s_waitcnt vmcnt(0)" ::: "memory");
    }
    __builtin_amdgcn_s_barrier();

    cb = (cb == 2) ? 0 : cb + 1;
    sb = (sb == 2) ? 0 : sb + 1;
    kst += 32;
  }
#undef STAGE8

#pragma unroll
  for (int n = 0; n < 4; ++n) {
    const long col = col0 + wc * 64 + n * 16 + c;
    const float bv = bias[col];
#pragma unroll
    for (int m = 0; m < 4; ++m) {
      const long rowb = row0 + wr * 64 + m * 16 + g * 4;
#pragma unroll
      for (int r = 0; r < 4; ++r) {
        float v = acc[m][n][r] + bv;
        const long idx = (rowb + r) * N + col;
        if (MODE == 0) {
          ((bf16*)out)[idx] = (bf16)v;
        } else if (MODE == 1) {
          ((float*)out)[idx] = res[idx] + v;
        } else {
          float sw = v / (1.f + __expf(-v));
          ((bf16*)out)[idx] = (bf16)sw;
        }
      }
    }
  }
}

// ---- flash attention v6: QBLK=256, 8 waves, 3-buffer K/V ring with
// DEPTH-2 counted prefetch: tiles t+1,t+2 in flight across barriers
// (vmcnt(4) steady, 2 -> 0 at tail). LDS ~65 KB -> 2 blocks/CU.
__global__ __launch_bounds__(512) void attn_fwd(
    const bf16* __restrict__ Q, const bf16* __restrict__ Kt,
    const bf16* __restrict__ VT, bf16* __restrict__ O) {
  __shared__ bf16 Ks[3][64 * 64];
  __shared__ bf16 Vs[3][64 * 64];
  __shared__ bf16 Pl[8][2][16 * 68];
  int t = threadIdx.x;
  int w = t >> 6, l = t & 63;
  int c = l & 15, g = l >> 4;
  int bid = blockIdx.x;
  int qt = bid >> 7, bh = bid & 127;
  int b = bh >> 4, h = bh & 15;
  int q0 = qt * 256 + w * 32;
  int swz = (c & 7) << 4;

  bf16x8 qf[2][2];
  const bf16* Qbase = Q + (long)(b * NS) * ND + h * NDK;
#pragma unroll
  for (int sj = 0; sj < 2; ++sj) {
    const bf16* qr = Qbase + (long)(q0 + sj * 16 + c) * ND + g * 8;
    qf[sj][0] = *(const bf16x8*)qr;
    qf[sj][1] = *(const bf16x8*)(qr + 32);
  }

  const bf16* Kg = Kt + (long)(b * NS) * ND + h * NDK;
  const bf16* Vg = VT + (long)(b * NH + h) * NDK * NS;

  int sr = l >> 3;
  int sc8 = 8 * ((l & 7) ^ sr);

  f32x4 o[2][4];
#pragma unroll
  for (int sj = 0; sj < 2; ++sj)
#pragma unroll
    for (int ds = 0; ds < 4; ++ds) o[sj][ds] = (f32x4){0.f, 0.f, 0.f, 0.f};
  float mx[2] = {-1e30f, -1e30f};
  float lsum[2] = {0.f, 0.f};

#define STAGEA(BUF, KV)                                                       \
  {                                                                           \
    int row = w * 8 + sr;                                                     \
    gload16(Kg + (long)((KV) + row) * ND + sc8, &Ks[BUF][(w * 8) * 64]);      \
    gload16(Vg + (long)row * NS + (KV) + sc8, &Vs[BUF][(w * 8) * 64]);        \
  }

  STAGEA(0, 0);
  STAGEA(1, 64);

  int buf = 0;
  for (int it = 0; it < NS / 64; ++it) {
    if (it + 2 < NS / 64) {
      int sb = (buf == 0) ? 2 : (buf - 1);  // slot (buf+2)%3
      STAGEA(sb, (it + 2) * 64);
      asm volatile("s_waitcnt vmcnt(4)" ::: "memory");  // tile it landed
    } else if (it + 1 < NS / 64) {
      asm volatile("s_waitcnt vmcnt(2)" ::: "memory");
    } else {
      asm volatile("s_waitcnt vmcnt(0)" ::: "memory");
    }
    __builtin_amdgcn_s_barrier();  // publish tile it (raw, keeps prefetch)

    f32x4 sv[2][4];
#pragma unroll
    for (int sj = 0; sj < 2; ++sj)
#pragma unroll
      for (int kt = 0; kt < 4; ++kt) sv[sj][kt] = (f32x4){0.f, 0.f, 0.f, 0.f};
    __builtin_amdgcn_s_setprio(1);
#pragma unroll
    for (int kt = 0; kt < 4; ++kt) {
      const char* kr = (const char*)&Ks[buf][(kt * 16 + c) * 64];
      bf16x8 ka0 = *(const bf16x8*)(kr + ((g * 16) ^ swz));
      bf16x8 ka1 = *(const bf16x8*)(kr + ((64 + g * 16) ^ swz));
#pragma unroll
      for (int sj = 0; sj < 2; ++sj) {
        sv[sj][kt] = __builtin_amdgcn_mfma_f32_16x16x32_bf16(ka0, qf[sj][0], sv[sj][kt], 0, 0, 0);
        sv[sj][kt] = __builtin_amdgcn_mfma_f32_16x16x32_bf16(ka1, qf[sj][1], sv[sj][kt], 0, 0, 0);
      }
    }
    __builtin_amdgcn_s_setprio(0);

    float pm[2];
#pragma unroll
    for (int sj = 0; sj < 2; ++sj) {
      float m = -1e30f;
#pragma unroll
      for (int kt = 0; kt < 4; ++kt)
#pragma unroll
        for (int r = 0; r < 4; ++r) {
          sv[sj][kt][r] *= 0.125f;
          m = fmaxf(m, sv[sj][kt][r]);
        }
      m = fmaxf(m, __shfl_xor(m, 16));
      m = fmaxf(m, __shfl_xor(m, 32));
      pm[sj] = m;
    }
    int cond = (pm[0] <= mx[0] + 8.f) && (pm[1] <= mx[1] + 8.f);
    if (!__all(cond)) {
#pragma unroll
      for (int sj = 0; sj < 2; ++sj) {
        float mn = fmaxf(mx[sj], pm[sj]);
        float sc = __expf(mx[sj] - mn);
        mx[sj] = mn;
        lsum[sj] *= sc;
#pragma unroll
        for (int ds = 0; ds < 4; ++ds)
#pragma unroll
          for (int r = 0; r < 4; ++r) o[sj][ds][r] *= sc;
      }
    }
#pragma unroll
    for (int sj = 0; sj < 2; ++sj) {
      float rs = 0.f;
#pragma unroll
      for (int kt = 0; kt < 4; ++kt) {
        bf16x4 pw;
#pragma unroll
        for (int r = 0; r < 4; ++r) {
          float e = __expf(sv[sj][kt][r] - mx[sj]);
          rs += e;
          pw[r] = (bf16)e;
        }
        *(bf16x4*)&Pl[w][sj][c * 68 + kt * 16 + 4 * g] = pw;
      }
      rs += __shfl_xor(rs, 16);
      rs += __shfl_xor(rs, 32);
      lsum[sj] += rs;
    }
    asm volatile("s_waitcnt lgkmcnt(0)" ::: "memory");
    __builtin_amdgcn_sched_barrier(0);

    __builtin_amdgcn_s_setprio(1);
#pragma unroll
    for (int ks = 0; ks < 2; ++ks) {
      bf16x8 pb0 = *(const bf16x8*)&Pl[w][0][c * 68 + ks * 32 + g * 8];
      bf16x8 pb1 = *(const bf16x8*)&Pl[w][1][c * 68 + ks * 32 + g * 8];
#pragma unroll
      for (int ds = 0; ds < 4; ++ds) {
        const char* vr = (const char*)&Vs[buf][(ds * 16 + c) * 64];
        bf16x8 va = *(const bf16x8*)(vr + ((ks * 64 + g * 16) ^ swz));
        o[0][ds] = __builtin_amdgcn_mfma_f32_16x16x32_bf16(va, pb0, o[0][ds], 0, 0, 0);
        o[1][ds] = __builtin_amdgcn_mfma_f32_16x16x32_bf16(va, pb1, o[1][ds], 0, 0, 0);
      }
    }
    __builtin_amdgcn_s_setprio(0);
    __builtin_amdgcn_s_barrier();  // raw: reads of buf done before its reuse
    buf = (buf == 2) ? 0 : buf + 1;
  }

#pragma unroll
  for (int sj = 0; sj < 2; ++sj) {
    float inv = 1.f / lsum[sj];
    bf16* Orow = O + (long)(b * NS + q0 + sj * 16 + c) * ND + h * NDK;
#pragma unroll
    for (int ds = 0; ds < 4; ++ds) {
      bf16x4 ov;
#pragma unroll
      for (int r = 0; r < 4; ++r) ov[r] = (bf16)(o[sj][ds][r] * inv);
      *(bf16x4*)(Orow + ds * 16 + 4 * g) = ov;
    }
  }
#undef STAGEA
}

extern "C" void kernel_launch(void* const* d_in, const int* in_sizes, int n_in,
                              void* d_out, int out_size, void* d_ws, size_t ws_size,
                              hipStream_t stream) {
  (void)in_sizes; (void)n_in; (void)out_size; (void)ws_size;
  const float* x = (const float*)d_in[0];
  const float* y = (const float*)d_in[1];
  const float* x_pos = (const float*)d_in[2];
  const float* y_pos = (const float*)d_in[3];

  char* ws = (char*)d_ws;
  const size_t MB = 1ull << 20;
  bf16* Wt[8];
  for (int i = 0; i < 8; ++i) Wt[i] = (bf16*)(ws + (size_t)i * 2 * MB);
  bf16* W1T = (bf16*)(ws + 16 * MB);
  bf16* W2T = (bf16*)(ws + 24 * MB);
  float* xres = (float*)(ws + 32 * MB);
  bf16* x2 = (bf16*)(ws + 64 * MB);
  bf16* qk = (bf16*)(ws + 80 * MB);
  bf16* y2 = (bf16*)(ws + 96 * MB);
  bf16* yk = (bf16*)(ws + 112 * MB);
  bf16* Qb = (bf16*)(ws + 128 * MB);
  bf16* Kb = (bf16*)(ws + 144 * MB);
  bf16* Kb2 = (bf16*)(ws + 160 * MB);
  bf16* VTb = (bf16*)(ws + 176 * MB);
  bf16* Ob = (bf16*)(ws + 192 * MB);
  bf16* VTb2 = (bf16*)(ws + 208 * MB);
  bf16* hb = (bf16*)(ws + 128 * MB);  // FFN: aliases Qb..VTb (dead then)

  dim3 tb(32, 8);
  WAll wa;
  for (int i = 0; i < 8; ++i) wa.w[i] = (const float*)d_in[4 + 2 * i];
  wa.w[8] = (const float*)d_in[20];
  wa.w[9] = (const float*)d_in[22];
  wconv_all<<<16384, tb, 0, stream>>>(wa, (bf16*)ws, W1T, W2T);

  const float* ln1g = (const float*)d_in[24]; const float* ln1b = (const float*)d_in[25];
  const float* ln2g = (const float*)d_in[26]; const float* ln2b = (const float*)d_in[27];
  const float* ln3g = (const float*)d_in[28]; const float* ln3b = (const float*)d_in[29];
  const float* ln4g = (const float*)d_in[30]; const float* ln4b = (const float*)d_in[31];

  dim3 gD(64, 8);      // 128^2 tiles
  dim3 gQKV(64, 8, 5); // mega-QKV: 2560 blocks
  dim3 gF1(32, 32);    // 256x128 tiles for FFN1

  // ---- LN1 + LN3 fused ----
  ln_fused2<<<16384, 256, 0, stream>>>(x, ln1g, ln1b, x_pos, x2, qk,
                                       y, ln3g, ln3b, y_pos, y2, yk);

  // ---- mega-QKV: self Q,K,V + cross K,V in ONE launch ----
  Jobs5 jobs;
  jobs.j[0] = {qk, Wt[0], (const float*)d_in[5], Qb, 0};    // self Q
  jobs.j[1] = {qk, Wt[1], (const float*)d_in[7], Kb, 0};    // self K
  jobs.j[2] = {x2, Wt[2], (const float*)d_in[9], VTb, 3};   // self V -> VT
  jobs.j[3] = {yk, Wt[5], (const float*)d_in[15], Kb2, 0};  // cross K
  jobs.j[4] = {y2, Wt[6], (const float*)d_in[17], VTb2, 3}; // cross V -> VT
  gemm_multi<<<gQKV, 256, 0, stream>>>(jobs);

  // ---- self-attention ----
  attn_fwd<<<512, 512, 0, stream>>>(Qb, Kb, VTb, Ob);
  gemm_bt<1><<<gD, 256, 0, stream>>>(Ob, Wt[3], (const float*)d_in[11], x, xres, 8192, 1024, 1024);

  // ---- cross-attention ----
  ln_fused<<<8192, 256, 0, stream>>>(xres, ln2g, ln2b, x_pos, nullptr, qk);
  gemm_bt<0><<<gD, 256, 0, stream>>>(qk, Wt[4], (const float*)d_in[13], nullptr, Qb, 8192, 1024, 1024);
  attn_fwd<<<512, 512, 0, stream>>>(Qb, Kb2, VTb2, Ob);
  gemm_bt<1><<<gD, 256, 0, stream>>>(Ob, Wt[7], (const float*)d_in[19], xres, xres, 8192, 1024, 1024);

  // ---- FFN ----
  ln_fused<<<8192, 256, 0, stream>>>(xres, ln4g, ln4b, nullptr, x2, nullptr);
  gemm_bt8<2><<<gF1, 512, 0, stream>>>(x2, W1T, (const float*)d_in[21], nullptr, hb, 8192, 4096, 1024);
  gemm_bt<1><<<gD, 256, 0, stream>>>(hb, W2T, (const float*)d_in[23], xres, (float*)d_out, 8192, 1024, 4096);
}

// Round 17
// 621.439 us; speedup vs baseline: 1.0359x; 1.0359x over previous
//
#include <hip/hip_runtime.h>
#include <hip/hip_bf16.h>

#define NB 8
#define NS 1024
#define ND 1024
#define NH 16
#define NDK 64
#define NDFF 4096

typedef __bf16 bf16;
typedef __attribute__((ext_vector_type(8))) __bf16 bf16x8;
typedef __attribute__((ext_vector_type(4))) __bf16 bf16x4;
typedef __attribute__((ext_vector_type(4))) float f32x4;

__device__ __forceinline__ void gload16(const bf16* g, bf16* l) {
  __builtin_amdgcn_global_load_lds(
      (const __attribute__((address_space(1))) void*)g,
      (__attribute__((address_space(3))) void*)l, 16, 0, 0);
}

// ---- weight convert + transpose: W f32 [K][N] -> WT bf16 [N][K] ----
__global__ void wconv_t(const float* __restrict__ W, bf16* __restrict__ WT,
                        int K, int N) {
  __shared__ float tile[32][33];
  int n0 = blockIdx.x * 32, k0 = blockIdx.y * 32;
  int tx = threadIdx.x, ty = threadIdx.y;
#pragma unroll
  for (int i2 = 0; i2 < 4; ++i2) {
    int i = ty + i2 * 8;
    tile[i][tx] = W[(long)(k0 + i) * N + n0 + tx];
  }
  __syncthreads();
#pragma unroll
  for (int i2 = 0; i2 < 4; ++i2) {
    int i = ty + i2 * 8;
    WT[(long)(n0 + i) * K + k0 + tx] = (bf16)tile[tx][i];
  }
}

// ---- fused 8x square (1024x1024) weight convert in one launch ----
struct WPtrs { const float* w[8]; };
__global__ void wconv8(WPtrs wp, bf16* __restrict__ dst) {
  __shared__ float tile[32][33];
  int n0 = blockIdx.x * 32, k0 = blockIdx.y * 32;
  const float* W = wp.w[blockIdx.z];
  bf16* WT = dst + (size_t)blockIdx.z * (1024 * 1024);
  int tx = threadIdx.x, ty = threadIdx.y;
#pragma unroll
  for (int i2 = 0; i2 < 4; ++i2) {
    int i = ty + i2 * 8;
    tile[i][tx] = W[(long)(k0 + i) * 1024 + n0 + tx];
  }
  __syncthreads();
#pragma unroll
  for (int i2 = 0; i2 < 4; ++i2) {
    int i = ty + i2 * 8;
    WT[(long)(n0 + i) * 1024 + k0 + tx] = (bf16)tile[tx][i];
  }
}

// ---- fused layernorm body ----
__device__ __forceinline__ void ln_body(
    const float* in, const float* gam, const float* bet, const float* pos,
    bf16* out_ln, bf16* out_lnpos, long row) {
  int t = threadIdx.x;  // 256
  float4 v = ((const float4*)(in + row * ND))[t];
  float s = v.x + v.y + v.z + v.w;
  float s2 = v.x * v.x + v.y * v.y + v.z * v.z + v.w * v.w;
#pragma unroll
  for (int m = 32; m >= 1; m >>= 1) {
    s += __shfl_xor(s, m);
    s2 += __shfl_xor(s2, m);
  }
  __shared__ float red[8];
  if ((t & 63) == 0) {
    red[t >> 6] = s;
    red[4 + (t >> 6)] = s2;
  }
  __syncthreads();
  float ts = red[0] + red[1] + red[2] + red[3];
  float ts2 = red[4] + red[5] + red[6] + red[7];
  float mu = ts * (1.0f / ND);
  float var = ts2 * (1.0f / ND) - mu * mu;
  float rstd = rsqrtf(var + 1e-5f);
  float4 g4 = ((const float4*)gam)[t];
  float4 b4 = ((const float4*)bet)[t];
  float o0 = (v.x - mu) * rstd * g4.x + b4.x;
  float o1 = (v.y - mu) * rstd * g4.y + b4.y;
  float o2 = (v.z - mu) * rstd * g4.z + b4.z;
  float o3 = (v.w - mu) * rstd * g4.w + b4.w;
  if (out_ln) {
    bf16x4 q;
    q[0] = (bf16)o0; q[1] = (bf16)o1; q[2] = (bf16)o2; q[3] = (bf16)o3;
    *(bf16x4*)(out_ln + row * ND + t * 4) = q;
  }
  if (out_lnpos) {
    float4 p4 = ((const float4*)(pos + row * ND))[t];
    bf16x4 q;
    q[0] = (bf16)(o0 + p4.x); q[1] = (bf16)(o1 + p4.y);
    q[2] = (bf16)(o2 + p4.z); q[3] = (bf16)(o3 + p4.w);
    *(bf16x4*)(out_lnpos + row * ND + t * 4) = q;
  }
}

__global__ void ln_fused(const float* __restrict__ in, const float* __restrict__ gam,
                         const float* __restrict__ bet, const float* __restrict__ pos,
                         bf16* __restrict__ out_ln, bf16* __restrict__ out_lnpos) {
  ln_body(in, gam, bet, pos, out_ln, out_lnpos, blockIdx.x);
}

__global__ void ln_fused2(
    const float* in0, const float* g0, const float* be0, const float* p0,
    bf16* oln0, bf16* olp0,
    const float* in1, const float* g1, const float* be1, const float* p1,
    bf16* oln1, bf16* olp1) {
  int sel = blockIdx.x >> 13;
  long row = blockIdx.x & 8191;
  if (sel == 0)
    ln_body(in0, g0, be0, p0, oln0, olp0, row);
  else
    ln_body(in1, g1, be1, p1, oln1, olp1, row);
}

// ==== GEMM v6 core: BM=BN=128, BK=32, 256 thr, 3-slot ring (48 KB ->
// 3 blocks/CU), stage t+2, counted vmcnt(4), 0-conflict swizzle.
// mode: 0 bf16; 1 f32 res+v; 2 bf16 swish; 3 bf16 VT-layout.
template <int MODE>
__device__ __forceinline__ void gemm_core(
    const bf16* A, const bf16* WT, const float* bias, const float* res,
    void* out, int N, int K, int mode_rt) {
  __shared__ bf16 SA[3][128 * 32];
  __shared__ bf16 SB[3][128 * 32];
  const int t = threadIdx.x;
  const int w = t >> 6, l = t & 63;
  const int wr = w >> 1, wc = w & 1;
  const int c = l & 15, g = l >> 4;
  const long row0 = (long)blockIdx.x * 128;
  const long col0 = (long)blockIdx.y * 128;
  const int NT = K >> 5;

  f32x4 acc[4][4];
#pragma unroll
  for (int m = 0; m < 4; ++m)
#pragma unroll
    for (int n = 0; n < 4; ++n) acc[m][n] = (f32x4){0.f, 0.f, 0.f, 0.f};

  const int srow = l >> 2;
  const int sslot = 8 * ((l & 3) ^ ((l >> 3) & 3));
  const bf16* Ag0 = A + (row0 + w * 16 + srow) * (long)K + sslot;
  const bf16* Ag1 = Ag0 + 64 * (long)K;
  const bf16* Bg0 = WT + (col0 + w * 16 + srow) * (long)K + sslot;
  const bf16* Bg1 = Bg0 + 64 * (long)K;
  bf16* const SAf = &SA[0][0];
  bf16* const SBf = &SB[0][0];

#define STAGEC(SL, KK)                                           \
  do {                                                           \
    gload16(Ag0 + (KK), SAf + (SL) * 4096 + (w * 16) * 32);      \
    gload16(Ag1 + (KK), SAf + (SL) * 4096 + (64 + w * 16) * 32); \
    gload16(Bg0 + (KK), SBf + (SL) * 4096 + (w * 16) * 32);      \
    gload16(Bg1 + (KK), SBf + (SL) * 4096 + (64 + w * 16) * 32); \
  } while (0)

  STAGEC(0, 0);
  STAGEC(1, 32);

  const int rsw = (g ^ ((c >> 1) & 3)) * 8;
  int aoff[4], boff[4];
#pragma unroll
  for (int m = 0; m < 4; ++m) aoff[m] = (wr * 64 + m * 16 + c) * 32 + rsw;
#pragma unroll
  for (int n = 0; n < 4; ++n) boff[n] = (wc * 64 + n * 16 + c) * 32 + rsw;

  asm volatile("s_waitcnt vmcnt(4)" ::: "memory");
  __builtin_amdgcn_s_barrier();

  int cb = 0, sb = 2, kst = 64;
  for (int tt = 0; tt < NT; ++tt) {
    const int ca = cb * 4096;
    bf16x8 af[4], bfr[4];
#pragma unroll
    for (int m = 0; m < 4; ++m) af[m] = *(const bf16x8*)(SAf + ca + aoff[m]);
#pragma unroll
    for (int n = 0; n < 4; ++n) bfr[n] = *(const bf16x8*)(SBf + ca + boff[n]);

    if (tt + 2 < NT) STAGEC(sb, kst);

    __builtin_amdgcn_s_barrier();
    asm volatile("s_waitcnt lgkmcnt(0)" ::: "memory");
    __builtin_amdgcn_sched_barrier(0);
    __builtin_amdgcn_s_setprio(1);
#pragma unroll
    for (int m = 0; m < 4; ++m)
#pragma unroll
      for (int n = 0; n < 4; ++n)
        acc[m][n] = __builtin_amdgcn_mfma_f32_16x16x32_bf16(af[m], bfr[n], acc[m][n], 0, 0, 0);
    __builtin_amdgcn_s_setprio(0);

    if (tt + 2 < NT) {
      asm volatile("s_waitcnt vmcnt(4)" ::: "memory");
    } else {
      asm volatile("s_waitcnt vmcnt(0)" ::: "memory");
    }
    __builtin_amdgcn_s_barrier();

    cb = (cb == 2) ? 0 : cb + 1;
    sb = (sb == 2) ? 0 : sb + 1;
    kst += 32;
  }
#undef STAGEC

  const int mode = (MODE >= 0) ? MODE : mode_rt;
  if (mode == 3) {
    bf16* VT = (bf16*)out;
#pragma unroll
    for (int n = 0; n < 4; ++n) {
      const long col = col0 + wc * 64 + n * 16 + c;
      const float bv = bias[col];
      const long h = col >> 6, dk = col & 63;
#pragma unroll
      for (int m = 0; m < 4; ++m) {
        const long rowb = row0 + wr * 64 + m * 16 + g * 4;
        const long b = rowb >> 10, s = rowb & 1023;
        bf16x4 ov;
#pragma unroll
        for (int r = 0; r < 4; ++r) ov[r] = (bf16)(acc[m][n][r] + bv);
        *(bf16x4*)(VT + (((b * NH + h) * NDK + dk) << 10) + s) = ov;
      }
    }
    return;
  }

#pragma unroll
  for (int n = 0; n < 4; ++n) {
    const long col = col0 + wc * 64 + n * 16 + c;
    const float bv = bias[col];
#pragma unroll
    for (int m = 0; m < 4; ++m) {
      const long rowb = row0 + wr * 64 + m * 16 + g * 4;
#pragma unroll
      for (int r = 0; r < 4; ++r) {
        float v = acc[m][n][r] + bv;
        const long idx = (rowb + r) * N + col;
        if (mode == 0) {
          ((bf16*)out)[idx] = (bf16)v;
        } else if (mode == 1) {
          ((float*)out)[idx] = res[idx] + v;
        } else {
          float sw = v / (1.f + __expf(-v));
          ((bf16*)out)[idx] = (bf16)sw;
        }
      }
    }
  }
}

template <int MODE>
__global__ __launch_bounds__(256) void gemm_bt(
    const bf16* __restrict__ A, const bf16* __restrict__ WT,
    const float* __restrict__ bias, const float* __restrict__ res,
    void* __restrict__ out, int M, int N, int K) {
  gemm_core<MODE>(A, WT, bias, res, out, N, K, 0);
}

struct GemmJob { const bf16* A; const bf16* WT; const float* bias; void* out; int mode; };
struct Jobs5 { GemmJob j[5]; };
__global__ __launch_bounds__(256) void gemm_multi(Jobs5 jobs) {
  const GemmJob& jb = jobs.j[blockIdx.z];
  gemm_core<-1>(jb.A, jb.WT, jb.bias, nullptr, jb.out, 1024, 1024, jb.mode);
}

// ---- GEMM-256sq: m201-style fine-interleaved template.
// BM=BN=256, BK=32, 512 thr, 8 waves as 2M x 4N (wave tile 128x64).
// 3-slot ring (96 KB, 1 block/CU). Per K-tile: ONE vmcnt + ONE barrier,
// then 2 phases {ds_read || 2 gload -> lgkmcnt(0) -> setprio 16 MFMA}.
// Stage tile T+2 during tile T. Gloads issue only AFTER the barrier all
// readers of the reused slot have passed -> race-free.
// MODE 2: bf16 swish out (FFN1 use).
template <int MODE>
__global__ __launch_bounds__(512) void gemm256(
    const bf16* __restrict__ A, const bf16* __restrict__ WT,
    const float* __restrict__ bias, void* __restrict__ out, int N, int K) {
  __shared__ bf16 SA[3][256 * 32];  // 48 KiB
  __shared__ bf16 SB[3][256 * 32];  // 48 KiB
  const int t = threadIdx.x;
  const int w = t >> 6, l = t & 63;
  const int wr = w >> 2;   // M-half (0/1): rows wr*128
  const int wcn = w & 3;   // N-quarter: cols wcn*64
  const int c = l & 15, g = l >> 4;
  const long row0 = (long)blockIdx.x * 256;
  const long col0 = (long)blockIdx.y * 256;
  const int NT = K >> 5;

  f32x4 acc[8][4];
#pragma unroll
  for (int m = 0; m < 8; ++m)
#pragma unroll
    for (int n = 0; n < 4; ++n) acc[m][n] = (f32x4){0.f, 0.f, 0.f, 0.f};

  // staging lane geometry (r12-verified swizzle): row = base + w*16 + (l>>2),
  // dest 16B-slot l&3, source slot (l&3)^((l>>3)&3) [= ^(row>>1)&3].
  const int srow = l >> 2;
  const int sslot = 8 * ((l & 3) ^ ((l >> 3) & 3));
  const bf16* Ag0 = A + (row0 + w * 16 + srow) * (long)K + sslot;
  const bf16* Ag1 = Ag0 + 128 * (long)K;
  const bf16* Bg0 = WT + (col0 + w * 16 + srow) * (long)K + sslot;
  const bf16* Bg1 = Bg0 + 128 * (long)K;
  bf16* const SAf = &SA[0][0];
  bf16* const SBf = &SB[0][0];

#define SGA(SL, KK)                                               \
  do {                                                            \
    gload16(Ag0 + (KK), SAf + (SL) * 8192 + (w * 16) * 32);       \
    gload16(Ag1 + (KK), SAf + (SL) * 8192 + (128 + w * 16) * 32); \
  } while (0)
#define SGB(SL, KK)                                               \
  do {                                                            \
    gload16(Bg0 + (KK), SBf + (SL) * 8192 + (w * 16) * 32);       \
    gload16(Bg1 + (KK), SBf + (SL) * 8192 + (128 + w * 16) * 32); \
  } while (0)

  // prologue: tiles 0,1 (8 gloads in flight, 4/wave... 4 instr each of A,B)
  SGA(0, 0); SGB(0, 0);
  SGA(1, 32); SGB(1, 32);

  // read offsets: frag row + c, 16B chunk g ^ ((c>>1)&3)
  const int rsw = (g ^ ((c >> 1) & 3)) * 8;
  int aoff[8], boff[4];
#pragma unroll
  for (int m = 0; m < 8; ++m) aoff[m] = (wr * 128 + m * 16 + c) * 32 + rsw;
#pragma unroll
  for (int n = 0; n < 4; ++n) boff[n] = (wcn * 64 + n * 16 + c) * 32 + rsw;

  int cb = 0, sb = 2, kst = 64;
  for (int tt = 0; tt < NT; ++tt) {
    // retire tile tt's 4 gloads (leave tt+1's 4 in flight)
    if (tt + 1 < NT) {
      asm volatile("s_waitcnt vmcnt(4)" ::: "memory");
    } else {
      asm volatile("s_waitcnt vmcnt(0)" ::: "memory");
    }
    __builtin_amdgcn_s_barrier();  // publish tile tt; all readers of slot sb passed

    const int ca = cb * 8192;
    const bool st = (tt + 2) < NT;

    // ---- phase a: n-frags 0,1 ----
    bf16x8 af[8], bf0, bf1;
#pragma unroll
    for (int m = 0; m < 8; ++m) af[m] = *(const bf16x8*)(SAf + ca + aoff[m]);
    bf0 = *(const bf16x8*)(SBf + ca + boff[0]);
    bf1 = *(const bf16x8*)(SBf + ca + boff[1]);
    if (st) SGA(sb, kst);
    asm volatile("s_waitcnt lgkmcnt(0)" ::: "memory");
    __builtin_amdgcn_sched_barrier(0);
    __builtin_amdgcn_s_setprio(1);
#pragma unroll
    for (int m = 0; m < 8; ++m) {
      acc[m][0] = __builtin_amdgcn_mfma_f32_16x16x32_bf16(af[m], bf0, acc[m][0], 0, 0, 0);
      acc[m][1] = __builtin_amdgcn_mfma_f32_16x16x32_bf16(af[m], bf1, acc[m][1], 0, 0, 0);
    }
    __builtin_amdgcn_s_setprio(0);

    // ---- phase b: n-frags 2,3 (A-frags reused from registers) ----
    bf16x8 bf2 = *(const bf16x8*)(SBf + ca + boff[2]);
    bf16x8 bf3 = *(const bf16x8*)(SBf + ca + boff[3]);
    if (st) SGB(sb, kst);
    asm volatile("s_waitcnt lgkmcnt(0)" ::: "memory");
    __builtin_amdgcn_sched_barrier(0);
    __builtin_amdgcn_s_setprio(1);
#pragma unroll
    for (int m = 0; m < 8; ++m) {
      acc[m][2] = __builtin_amdgcn_mfma_f32_16x16x32_bf16(af[m], bf2, acc[m][2], 0, 0, 0);
      acc[m][3] = __builtin_amdgcn_mfma_f32_16x16x32_bf16(af[m], bf3, acc[m][3], 0, 0, 0);
    }
    __builtin_amdgcn_s_setprio(0);

    cb = (cb == 2) ? 0 : cb + 1;
    sb = (sb == 2) ? 0 : sb + 1;
    kst += 32;
  }
#undef SGA
#undef SGB

#pragma unroll
  for (int n = 0; n < 4; ++n) {
    const long col = col0 + wcn * 64 + n * 16 + c;
    const float bv = bias[col];
#pragma unroll
    for (int m = 0; m < 8; ++m) {
      const long rowb = row0 + wr * 128 + m * 16 + g * 4;
#pragma unroll
      for (int r = 0; r < 4; ++r) {
        float v = acc[m][n][r] + bv;
        const long idx = (rowb + r) * N + col;
        if (MODE == 0) {
          ((bf16*)out)[idx] = (bf16)v;
        } else {
          float sw = v / (1.f + __expf(-v));
          ((bf16*)out)[idx] = (bf16)sw;
        }
      }
    }
  }
}

// ---- flash attention v5 (round-14 proven): QBLK=256, 8 waves, 2-buffer,
// counted vmcnt(2), raw barriers ----
__global__ __launch_bounds__(512) void attn_fwd(
    const bf16* __restrict__ Q, const bf16* __restrict__ Kt,
    const bf16* __restrict__ VT, bf16* __restrict__ O) {
  __shared__ bf16 Ks[2][64 * 64];
  __shared__ bf16 Vs[2][64 * 64];
  __shared__ bf16 Pl[8][2][16 * 68];
  int t = threadIdx.x;
  int w = t >> 6, l = t & 63;
  int c = l & 15, g = l >> 4;
  int bid = blockIdx.x;
  int qt = bid >> 7, bh = bid & 127;
  int b = bh >> 4, h = bh & 15;
  int q0 = qt * 256 + w * 32;
  int swz = (c & 7) << 4;

  bf16x8 qf[2][2];
  const bf16* Qbase = Q + (long)(b * NS) * ND + h * NDK;
#pragma unroll
  for (int sj = 0; sj < 2; ++sj) {
    const bf16* qr = Qbase + (long)(q0 + sj * 16 + c) * ND + g * 8;
    qf[sj][0] = *(const bf16x8*)qr;
    qf[sj][1] = *(const bf16x8*)(qr + 32);
  }

  const bf16* Kg = Kt + (long)(b * NS) * ND + h * NDK;
  const bf16* Vg = VT + (long)(b * NH + h) * NDK * NS;

  int sr = l >> 3;
  int sc8 = 8 * ((l & 7) ^ sr);

  f32x4 o[2][4];
#pragma unroll
  for (int sj = 0; sj < 2; ++sj)
#pragma unroll
    for (int ds = 0; ds < 4; ++ds) o[sj][ds] = (f32x4){0.f, 0.f, 0.f, 0.f};
  float mx[2] = {-1e30f, -1e30f};
  float lsum[2] = {0.f, 0.f};

#define STAGEA(BUF, KV)                                                       \
  {                                                                           \
    int row = w * 8 + sr;                                                     \
    gload16(Kg + (long)((KV) + row) * ND + sc8, &Ks[BUF][(w * 8) * 64]);      \
    gload16(Vg + (long)row * NS + (KV) + sc8, &Vs[BUF][(w * 8) * 64]);        \
  }

  STAGEA(0, 0);

  int buf = 0;
  for (int it = 0; it < NS / 64; ++it) {
    if (it + 1 < NS / 64) {
      STAGEA(buf ^ 1, (it + 1) * 64);
      asm volatile("s_waitcnt vmcnt(2)" ::: "memory");
    } else {
      asm volatile("s_waitcnt vmcnt(0)" ::: "memory");
    }
    __builtin_amdgcn_s_barrier();

    f32x4 sv[2][4];
#pragma unroll
    for (int sj = 0; sj < 2; ++sj)
#pragma unroll
      for (int kt = 0; kt < 4; ++kt) sv[sj][kt] = (f32x4){0.f, 0.f, 0.f, 0.f};
    __builtin_amdgcn_s_setprio(1);
#pragma unroll
    for (int kt = 0; kt < 4; ++kt) {
      const char* kr = (const char*)&Ks[buf][(kt * 16 + c) * 64];
      bf16x8 ka0 = *(const bf16x8*)(kr + ((g * 16) ^ swz));
      bf16x8 ka1 = *(const bf16x8*)(kr + ((64 + g * 16) ^ swz));
#pragma unroll
      for (int sj = 0; sj < 2; ++sj) {
        sv[sj][kt] = __builtin_amdgcn_mfma_f32_16x16x32_bf16(ka0, qf[sj][0], sv[sj][kt], 0, 0, 0);
        sv[sj][kt] = __builtin_amdgcn_mfma_f32_16x16x32_bf16(ka1, qf[sj][1], sv[sj][kt], 0, 0, 0);
      }
    }
    __builtin_amdgcn_s_setprio(0);

    float pm[2];
#pragma unroll
    for (int sj = 0; sj < 2; ++sj) {
      float m = -1e30f;
#pragma unroll
      for (int kt = 0; kt < 4; ++kt)
#pragma unroll
        for (int r = 0; r < 4; ++r) {
          sv[sj][kt][r] *= 0.125f;
          m = fmaxf(m, sv[sj][kt][r]);
        }
      m = fmaxf(m, __shfl_xor(m, 16));
      m = fmaxf(m, __shfl_xor(m, 32));
      pm[sj] = m;
    }
    int cond = (pm[0] <= mx[0] + 8.f) && (pm[1] <= mx[1] + 8.f);
    if (!__all(cond)) {
#pragma unroll
      for (int sj = 0; sj < 2; ++sj) {
        float mn = fmaxf(mx[sj], pm[sj]);
        float sc = __expf(mx[sj] - mn);
        mx[sj] = mn;
        lsum[sj] *= sc;
#pragma unroll
        for (int ds = 0; ds < 4; ++ds)
#pragma unroll
          for (int r = 0; r < 4; ++r) o[sj][ds][r] *= sc;
      }
    }
#pragma unroll
    for (int sj = 0; sj < 2; ++sj) {
      float rs = 0.f;
#pragma unroll
      for (int kt = 0; kt < 4; ++kt) {
        bf16x4 pw;
#pragma unroll
        for (int r = 0; r < 4; ++r) {
          float e = __expf(sv[sj][kt][r] - mx[sj]);
          rs += e;
          pw[r] = (bf16)e;
        }
        *(bf16x4*)&Pl[w][sj][c * 68 + kt * 16 + 4 * g] = pw;
      }
      rs += __shfl_xor(rs, 16);
      rs += __shfl_xor(rs, 32);
      lsum[sj] += rs;
    }
    asm volatile("s_waitcnt lgkmcnt(0)" ::: "memory");
    __builtin_amdgcn_sched_barrier(0);

    __builtin_amdgcn_s_setprio(1);
#pragma unroll
    for (int ks = 0; ks < 2; ++ks) {
      bf16x8 pb0 = *(const bf16x8*)&Pl[w][0][c * 68 + ks * 32 + g * 8];
      bf16x8 pb1 = *(const bf16x8*)&Pl[w][1][c * 68 + ks * 32 + g * 8];
#pragma unroll
      for (int ds = 0; ds < 4; ++ds) {
        const char* vr = (const char*)&Vs[buf][(ds * 16 + c) * 64];
        bf16x8 va = *(const bf16x8*)(vr + ((ks * 64 + g * 16) ^ swz));
        o[0][ds] = __builtin_amdgcn_mfma_f32_16x16x32_bf16(va, pb0, o[0][ds], 0, 0, 0);
        o[1][ds] = __builtin_amdgcn_mfma_f32_16x16x32_bf16(va, pb1, o[1][ds], 0, 0, 0);
      }
    }
    __builtin_amdgcn_s_setprio(0);
    __builtin_amdgcn_s_barrier();
    buf ^= 1;
  }

#pragma unroll
  for (int sj = 0; sj < 2; ++sj) {
    float inv = 1.f / lsum[sj];
    bf16* Orow = O + (long)(b * NS + q0 + sj * 16 + c) * ND + h * NDK;
#pragma unroll
    for (int ds = 0; ds < 4; ++ds) {
      bf16x4 ov;
#pragma unroll
      for (int r = 0; r < 4; ++r) ov[r] = (bf16)(o[sj][ds][r] * inv);
      *(bf16x4*)(Orow + ds * 16 + 4 * g) = ov;
    }
  }
#undef STAGEA
}

extern "C" void kernel_launch(void* const* d_in, const int* in_sizes, int n_in,
                              void* d_out, int out_size, void* d_ws, size_t ws_size,
                              hipStream_t stream) {
  (void)in_sizes; (void)n_in; (void)out_size; (void)ws_size;
  const float* x = (const float*)d_in[0];
  const float* y = (const float*)d_in[1];
  const float* x_pos = (const float*)d_in[2];
  const float* y_pos = (const float*)d_in[3];

  char* ws = (char*)d_ws;
  const size_t MB = 1ull << 20;
  bf16* Wt[8];
  for (int i = 0; i < 8; ++i) Wt[i] = (bf16*)(ws + (size_t)i * 2 * MB);
  bf16* W1T = (bf16*)(ws + 16 * MB);
  bf16* W2T = (bf16*)(ws + 24 * MB);
  float* xres = (float*)(ws + 32 * MB);
  bf16* x2 = (bf16*)(ws + 64 * MB);
  bf16* qk = (bf16*)(ws + 80 * MB);
  bf16* y2 = (bf16*)(ws + 96 * MB);
  bf16* yk = (bf16*)(ws + 112 * MB);
  bf16* Qb = (bf16*)(ws + 128 * MB);
  bf16* Kb = (bf16*)(ws + 144 * MB);
  bf16* Kb2 = (bf16*)(ws + 160 * MB);
  bf16* VTb = (bf16*)(ws + 176 * MB);
  bf16* Ob = (bf16*)(ws + 192 * MB);
  bf16* VTb2 = (bf16*)(ws + 208 * MB);
  bf16* hb = (bf16*)(ws + 128 * MB);  // FFN: aliases Qb..VTb (dead then)

  dim3 tb(32, 8);
  WPtrs wp;
  for (int i = 0; i < 8; ++i) wp.w[i] = (const float*)d_in[4 + 2 * i];
  wconv8<<<dim3(32, 32, 8), tb, 0, stream>>>(wp, (bf16*)ws);
  wconv_t<<<dim3(128, 32), tb, 0, stream>>>((const float*)d_in[20], W1T, 1024, 4096);
  wconv_t<<<dim3(32, 128), tb, 0, stream>>>((const float*)d_in[22], W2T, 4096, 1024);

  const float* ln1g = (const float*)d_in[24]; const float* ln1b = (const float*)d_in[25];
  const float* ln2g = (const float*)d_in[26]; const float* ln2b = (const float*)d_in[27];
  const float* ln3g = (const float*)d_in[28]; const float* ln3b = (const float*)d_in[29];
  const float* ln4g = (const float*)d_in[30]; const float* ln4b = (const float*)d_in[31];

  dim3 gD(64, 8);      // 128^2 tiles
  dim3 gQKV(64, 8, 5); // mega-QKV
  dim3 gF1(32, 16);    // gemm256 FFN1: 256^2 tiles

  // ---- LN1 + LN3 fused ----
  ln_fused2<<<16384, 256, 0, stream>>>(x, ln1g, ln1b, x_pos, x2, qk,
                                       y, ln3g, ln3b, y_pos, y2, yk);

  // ---- mega-QKV: self Q,K,V + cross K,V in ONE launch ----
  Jobs5 jobs;
  jobs.j[0] = {qk, Wt[0], (const float*)d_in[5], Qb, 0};
  jobs.j[1] = {qk, Wt[1], (const float*)d_in[7], Kb, 0};
  jobs.j[2] = {x2, Wt[2], (const float*)d_in[9], VTb, 3};
  jobs.j[3] = {yk, Wt[5], (const float*)d_in[15], Kb2, 0};
  jobs.j[4] = {y2, Wt[6], (const float*)d_in[17], VTb2, 3};
  gemm_multi<<<gQKV, 256, 0, stream>>>(jobs);

  // ---- self-attention ----
  attn_fwd<<<512, 512, 0, stream>>>(Qb, Kb, VTb, Ob);
  gemm_bt<1><<<gD, 256, 0, stream>>>(Ob, Wt[3], (const float*)d_in[11], x, xres, 8192, 1024, 1024);

  // ---- cross-attention ----
  ln_fused<<<8192, 256, 0, stream>>>(xres, ln2g, ln2b, x_pos, nullptr, qk);
  gemm_bt<0><<<gD, 256, 0, stream>>>(qk, Wt[4], (const float*)d_in[13], nullptr, Qb, 8192, 1024, 1024);
  attn_fwd<<<512, 512, 0, stream>>>(Qb, Kb2, VTb2, Ob);
  gemm_bt<1><<<gD, 256, 0, stream>>>(Ob, Wt[7], (const float*)d_in[19], xres, xres, 8192, 1024, 1024);

  // ---- FFN ----
  ln_fused<<<8192, 256, 0, stream>>>(xres, ln4g, ln4b, nullptr, x2, nullptr);
  gemm256<2><<<gF1, 512, 0, stream>>>(x2, W1T, (const float*)d_in[21], hb, 4096, 1024);
  gemm_bt<1><<<gD, 256, 0, stream>>>(hb, W2T, (const float*)d_in[23], xres, (float*)d_out, 8192, 1024, 4096);
}

// Round 18
// 611.710 us; speedup vs baseline: 1.0524x; 1.0159x over previous
//
#include <hip/hip_runtime.h>
#include <hip/hip_bf16.h>

#define NB 8
#define NS 1024
#define ND 1024
#define NH 16
#define NDK 64
#define NDFF 4096

typedef __bf16 bf16;
typedef __attribute__((ext_vector_type(8))) __bf16 bf16x8;
typedef __attribute__((ext_vector_type(4))) __bf16 bf16x4;
typedef __attribute__((ext_vector_type(4))) float f32x4;

__device__ __forceinline__ void gload16(const bf16* g, bf16* l) {
  __builtin_amdgcn_global_load_lds(
      (const __attribute__((address_space(1))) void*)g,
      (__attribute__((address_space(3))) void*)l, 16, 0, 0);
}

// ---- weight convert + transpose: W f32 [K][N] -> WT bf16 [N][K] ----
__global__ void wconv_t(const float* __restrict__ W, bf16* __restrict__ WT,
                        int K, int N) {
  __shared__ float tile[32][33];
  int n0 = blockIdx.x * 32, k0 = blockIdx.y * 32;
  int tx = threadIdx.x, ty = threadIdx.y;
#pragma unroll
  for (int i2 = 0; i2 < 4; ++i2) {
    int i = ty + i2 * 8;
    tile[i][tx] = W[(long)(k0 + i) * N + n0 + tx];
  }
  __syncthreads();
#pragma unroll
  for (int i2 = 0; i2 < 4; ++i2) {
    int i = ty + i2 * 8;
    WT[(long)(n0 + i) * K + k0 + tx] = (bf16)tile[tx][i];
  }
}

// ---- fused 8x square (1024x1024) weight convert in one launch ----
struct WPtrs { const float* w[8]; };
__global__ void wconv8(WPtrs wp, bf16* __restrict__ dst) {
  __shared__ float tile[32][33];
  int n0 = blockIdx.x * 32, k0 = blockIdx.y * 32;
  const float* W = wp.w[blockIdx.z];
  bf16* WT = dst + (size_t)blockIdx.z * (1024 * 1024);
  int tx = threadIdx.x, ty = threadIdx.y;
#pragma unroll
  for (int i2 = 0; i2 < 4; ++i2) {
    int i = ty + i2 * 8;
    tile[i][tx] = W[(long)(k0 + i) * 1024 + n0 + tx];
  }
  __syncthreads();
#pragma unroll
  for (int i2 = 0; i2 < 4; ++i2) {
    int i = ty + i2 * 8;
    WT[(long)(n0 + i) * 1024 + k0 + tx] = (bf16)tile[tx][i];
  }
}

// ---- fused layernorm: out_ln = bf16(LN(x)), out_lnpos = bf16(LN(x)+pos) ----
__global__ void ln_fused(const float* __restrict__ in, const float* __restrict__ gam,
                         const float* __restrict__ bet, const float* __restrict__ pos,
                         bf16* __restrict__ out_ln, bf16* __restrict__ out_lnpos) {
  long row = blockIdx.x;
  int t = threadIdx.x;  // 256
  float4 v = ((const float4*)(in + row * ND))[t];
  float s = v.x + v.y + v.z + v.w;
  float s2 = v.x * v.x + v.y * v.y + v.z * v.z + v.w * v.w;
#pragma unroll
  for (int m = 32; m >= 1; m >>= 1) {
    s += __shfl_xor(s, m);
    s2 += __shfl_xor(s2, m);
  }
  __shared__ float red[8];
  if ((t & 63) == 0) {
    red[t >> 6] = s;
    red[4 + (t >> 6)] = s2;
  }
  __syncthreads();
  float ts = red[0] + red[1] + red[2] + red[3];
  float ts2 = red[4] + red[5] + red[6] + red[7];
  float mu = ts * (1.0f / ND);
  float var = ts2 * (1.0f / ND) - mu * mu;
  float rstd = rsqrtf(var + 1e-5f);
  float4 g4 = ((const float4*)gam)[t];
  float4 b4 = ((const float4*)bet)[t];
  float o0 = (v.x - mu) * rstd * g4.x + b4.x;
  float o1 = (v.y - mu) * rstd * g4.y + b4.y;
  float o2 = (v.z - mu) * rstd * g4.z + b4.z;
  float o3 = (v.w - mu) * rstd * g4.w + b4.w;
  if (out_ln) {
    bf16x4 q;
    q[0] = (bf16)o0; q[1] = (bf16)o1; q[2] = (bf16)o2; q[3] = (bf16)o3;
    *(bf16x4*)(out_ln + row * ND + t * 4) = q;
  }
  if (out_lnpos) {
    float4 p4 = ((const float4*)(pos + row * ND))[t];
    bf16x4 q;
    q[0] = (bf16)(o0 + p4.x); q[1] = (bf16)(o1 + p4.y);
    q[2] = (bf16)(o2 + p4.z); q[3] = (bf16)(o3 + p4.w);
    *(bf16x4*)(out_lnpos + row * ND + t * 4) = q;
  }
}

// ---- GEMM v6 (round-12 proven best): BM=BN=128, BK=32, 256 thr (4 waves,
// 64x64/wave). 3-slot LDS ring (48 KB -> 3 blocks/CU). Stage tile t+2
// during t; counted vmcnt(4). Zero-conflict chunk swizzle.
// MODE 0: bf16 out. MODE 1: f32 out = res + v. MODE 2: bf16 swish(v).
// MODE 3: bf16 out written to VT layout [B*H][DK][S] (fused v-transpose).
template <int MODE>
__global__ __launch_bounds__(256) void gemm_bt(
    const bf16* __restrict__ A, const bf16* __restrict__ WT,
    const float* __restrict__ bias, const float* __restrict__ res,
    void* __restrict__ out, int M, int N, int K) {
  __shared__ bf16 SA[3][128 * 32];  // 24 KiB
  __shared__ bf16 SB[3][128 * 32];  // 24 KiB
  const int t = threadIdx.x;
  const int w = t >> 6, l = t & 63;
  const int wr = w >> 1, wc = w & 1;
  const int c = l & 15, g = l >> 4;
  const long row0 = (long)blockIdx.x * 128;
  const long col0 = (long)blockIdx.y * 128;
  const int NT = K >> 5;

  f32x4 acc[4][4];
#pragma unroll
  for (int m = 0; m < 4; ++m)
#pragma unroll
    for (int n = 0; n < 4; ++n) acc[m][n] = (f32x4){0.f, 0.f, 0.f, 0.f};

  const int srow = l >> 2;
  const int sslot = 8 * ((l & 3) ^ ((l >> 3) & 3));
  const bf16* Ag0 = A + (row0 + w * 16 + srow) * (long)K + sslot;
  const bf16* Ag1 = Ag0 + 64 * (long)K;
  const bf16* Bg0 = WT + (col0 + w * 16 + srow) * (long)K + sslot;
  const bf16* Bg1 = Bg0 + 64 * (long)K;
  bf16* const SAf = &SA[0][0];
  bf16* const SBf = &SB[0][0];

#define STAGE(SL, KK)                                            \
  do {                                                           \
    gload16(Ag0 + (KK), SAf + (SL) * 4096 + (w * 16) * 32);      \
    gload16(Ag1 + (KK), SAf + (SL) * 4096 + (64 + w * 16) * 32); \
    gload16(Bg0 + (KK), SBf + (SL) * 4096 + (w * 16) * 32);      \
    gload16(Bg1 + (KK), SBf + (SL) * 4096 + (64 + w * 16) * 32); \
  } while (0)

  STAGE(0, 0);
  STAGE(1, 32);

  const int rsw = (g ^ ((c >> 1) & 3)) * 8;
  int aoff[4], boff[4];
#pragma unroll
  for (int m = 0; m < 4; ++m) aoff[m] = (wr * 64 + m * 16 + c) * 32 + rsw;
#pragma unroll
  for (int n = 0; n < 4; ++n) boff[n] = (wc * 64 + n * 16 + c) * 32 + rsw;

  asm volatile("s_waitcnt vmcnt(4)" ::: "memory");
  __builtin_amdgcn_s_barrier();

  int cb = 0, sb = 2, kst = 64;
  for (int tt = 0; tt < NT; ++tt) {
    const int ca = cb * 4096;
    bf16x8 af[4], bfr[4];
#pragma unroll
    for (int m = 0; m < 4; ++m) af[m] = *(const bf16x8*)(SAf + ca + aoff[m]);
#pragma unroll
    for (int n = 0; n < 4; ++n) bfr[n] = *(const bf16x8*)(SBf + ca + boff[n]);

    if (tt + 2 < NT) STAGE(sb, kst);

    __builtin_amdgcn_s_barrier();
    asm volatile("s_waitcnt lgkmcnt(0)" ::: "memory");
    __builtin_amdgcn_sched_barrier(0);
    __builtin_amdgcn_s_setprio(1);
#pragma unroll
    for (int m = 0; m < 4; ++m)
#pragma unroll
      for (int n = 0; n < 4; ++n)
        acc[m][n] = __builtin_amdgcn_mfma_f32_16x16x32_bf16(af[m], bfr[n], acc[m][n], 0, 0, 0);
    __builtin_amdgcn_s_setprio(0);

    if (tt + 2 < NT) {
      asm volatile("s_waitcnt vmcnt(4)" ::: "memory");
    } else {
      asm volatile("s_waitcnt vmcnt(0)" ::: "memory");
    }
    __builtin_amdgcn_s_barrier();

    cb = (cb == 2) ? 0 : cb + 1;
    sb = (sb == 2) ? 0 : sb + 1;
    kst += 32;
  }
#undef STAGE

  if (MODE == 3) {
    bf16* VT = (bf16*)out;
#pragma unroll
    for (int n = 0; n < 4; ++n) {
      const long col = col0 + wc * 64 + n * 16 + c;
      const float bv = bias[col];
      const long h = col >> 6, dk = col & 63;
#pragma unroll
      for (int m = 0; m < 4; ++m) {
        const long rowb = row0 + wr * 64 + m * 16 + g * 4;
        const long b = rowb >> 10, s = rowb & 1023;
        bf16x4 ov;
#pragma unroll
        for (int r = 0; r < 4; ++r) ov[r] = (bf16)(acc[m][n][r] + bv);
        *(bf16x4*)(VT + (((b * NH + h) * NDK + dk) << 10) + s) = ov;
      }
    }
    return;
  }

#pragma unroll
  for (int n = 0; n < 4; ++n) {
    const long col = col0 + wc * 64 + n * 16 + c;
    const float bv = bias[col];
#pragma unroll
    for (int m = 0; m < 4; ++m) {
      const long rowb = row0 + wr * 64 + m * 16 + g * 4;
#pragma unroll
      for (int r = 0; r < 4; ++r) {
        float v = acc[m][n][r] + bv;
        const long idx = (rowb + r) * N + col;
        if (MODE == 0) {
          ((bf16*)out)[idx] = (bf16)v;
        } else if (MODE == 1) {
          ((float*)out)[idx] = res[idx] + v;
        } else {
          float sw = v / (1.f + __expf(-v));
          ((bf16*)out)[idx] = (bf16)sw;
        }
      }
    }
  }
}

// ---- GEMM v6-w8 (FFN1): BM=256, BN=128, BK=32, 512 thr.
// 3-slot ring (72 KB -> 2 blocks/CU); counted vmcnt(3). Measured 95us FFN1.
template <int MODE>
__global__ __launch_bounds__(512) void gemm_bt8(
    const bf16* __restrict__ A, const bf16* __restrict__ WT,
    const float* __restrict__ bias, const float* __restrict__ res,
    void* __restrict__ out, int M, int N, int K) {
  __shared__ bf16 SA[3][256 * 32];  // 48 KiB
  __shared__ bf16 SB[3][128 * 32];  // 24 KiB
  const int t = threadIdx.x;
  const int w = t >> 6, l = t & 63;
  const int wr = w >> 1, wc = w & 1;
  const int c = l & 15, g = l >> 4;
  const long row0 = (long)blockIdx.x * 256;
  const long col0 = (long)blockIdx.y * 128;
  const int NT = K >> 5;

  f32x4 acc[4][4];
#pragma unroll
  for (int m = 0; m < 4; ++m)
#pragma unroll
    for (int n = 0; n < 4; ++n) acc[m][n] = (f32x4){0.f, 0.f, 0.f, 0.f};

  const int srow = l >> 2;
  const int sslot = 8 * ((l & 3) ^ ((l >> 3) & 3));
  const bf16* Ag0 = A + (row0 + w * 16 + srow) * (long)K + sslot;
  const bf16* Ag1 = Ag0 + 128 * (long)K;
  const bf16* Bg0 = WT + (col0 + w * 16 + srow) * (long)K + sslot;
  bf16* const SAf = &SA[0][0];
  bf16* const SBf = &SB[0][0];

#define STAGE8(SL, KK)                                            \
  do {                                                            \
    gload16(Ag0 + (KK), SAf + (SL) * 8192 + (w * 16) * 32);       \
    gload16(Ag1 + (KK), SAf + (SL) * 8192 + (128 + w * 16) * 32); \
    gload16(Bg0 + (KK), SBf + (SL) * 4096 + (w * 16) * 32);       \
  } while (0)

  STAGE8(0, 0);
  STAGE8(1, 32);

  const int rsw = (g ^ ((c >> 1) & 3)) * 8;
  int aoff[4], boff[4];
#pragma unroll
  for (int m = 0; m < 4; ++m) aoff[m] = (wr * 64 + m * 16 + c) * 32 + rsw;
#pragma unroll
  for (int n = 0; n < 4; ++n) boff[n] = (wc * 64 + n * 16 + c) * 32 + rsw;

  asm volatile("s_waitcnt vmcnt(3)" ::: "memory");
  __builtin_amdgcn_s_barrier();

  int cb = 0, sb = 2, kst = 64;
  for (int tt = 0; tt < NT; ++tt) {
    bf16x8 af[4], bfr[4];
#pragma unroll
    for (int m = 0; m < 4; ++m) af[m] = *(const bf16x8*)(SAf + cb * 8192 + aoff[m]);
#pragma unroll
    for (int n = 0; n < 4; ++n) bfr[n] = *(const bf16x8*)(SBf + cb * 4096 + boff[n]);

    if (tt + 2 < NT) STAGE8(sb, kst);

    __builtin_amdgcn_s_barrier();
    asm volatile("s_waitcnt lgkmcnt(0)" ::: "memory");
    __builtin_amdgcn_sched_barrier(0);
    __builtin_amdgcn_s_setprio(1);
#pragma unroll
    for (int m = 0; m < 4; ++m)
#pragma unroll
      for (int n = 0; n < 4; ++n)
        acc[m][n] = __builtin_amdgcn_mfma_f32_16x16x32_bf16(af[m], bfr[n], acc[m][n], 0, 0, 0);
    __builtin_amdgcn_s_setprio(0);

    if (tt + 2 < NT) {
      asm volatile("s_waitcnt vmcnt(3)" ::: "memory");
    } else {
      asm volatile("s_waitcnt vmcnt(0)" ::: "memory");
    }
    __builtin_amdgcn_s_barrier();

    cb = (cb == 2) ? 0 : cb + 1;
    sb = (sb == 2) ? 0 : sb + 1;
    kst += 32;
  }
#undef STAGE8

#pragma unroll
  for (int n = 0; n < 4; ++n) {
    const long col = col0 + wc * 64 + n * 16 + c;
    const float bv = bias[col];
#pragma unroll
    for (int m = 0; m < 4; ++m) {
      const long rowb = row0 + wr * 64 + m * 16 + g * 4;
#pragma unroll
      for (int r = 0; r < 4; ++r) {
        float v = acc[m][n][r] + bv;
        const long idx = (rowb + r) * N + col;
        if (MODE == 0) {
          ((bf16*)out)[idx] = (bf16)v;
        } else if (MODE == 1) {
          ((float*)out)[idx] = res[idx] + v;
        } else {
          float sw = v / (1.f + __expf(-v));
          ((bf16*)out)[idx] = (bf16)sw;
        }
      }
    }
  }
}

// ---- flash attention v5: QBLK=256 via 8 waves/block, 2-buffer K/V,
// counted vmcnt(2), raw barriers (prefetch stays in flight). ----
__global__ __launch_bounds__(512) void attn_fwd(
    const bf16* __restrict__ Q, const bf16* __restrict__ Kt,
    const bf16* __restrict__ VT, bf16* __restrict__ O) {
  __shared__ bf16 Ks[2][64 * 64];
  __shared__ bf16 Vs[2][64 * 64];
  __shared__ bf16 Pl[8][2][16 * 68];
  int t = threadIdx.x;
  int w = t >> 6, l = t & 63;
  int c = l & 15, g = l >> 4;
  int bid = blockIdx.x;
  int qt = bid >> 7, bh = bid & 127;
  int b = bh >> 4, h = bh & 15;
  int q0 = qt * 256 + w * 32;
  int swz = (c & 7) << 4;

  bf16x8 qf[2][2];
  const bf16* Qbase = Q + (long)(b * NS) * ND + h * NDK;
#pragma unroll
  for (int sj = 0; sj < 2; ++sj) {
    const bf16* qr = Qbase + (long)(q0 + sj * 16 + c) * ND + g * 8;
    qf[sj][0] = *(const bf16x8*)qr;
    qf[sj][1] = *(const bf16x8*)(qr + 32);
  }

  const bf16* Kg = Kt + (long)(b * NS) * ND + h * NDK;
  const bf16* Vg = VT + (long)(b * NH + h) * NDK * NS;

  int sr = l >> 3;
  int sc8 = 8 * ((l & 7) ^ sr);

  f32x4 o[2][4];
#pragma unroll
  for (int sj = 0; sj < 2; ++sj)
#pragma unroll
    for (int ds = 0; ds < 4; ++ds) o[sj][ds] = (f32x4){0.f, 0.f, 0.f, 0.f};
  float mx[2] = {-1e30f, -1e30f};
  float lsum[2] = {0.f, 0.f};

#define STAGE(BUF, KV)                                                        \
  {                                                                           \
    int row = w * 8 + sr;                                                     \
    gload16(Kg + (long)((KV) + row) * ND + sc8, &Ks[BUF][(w * 8) * 64]);      \
    gload16(Vg + (long)row * NS + (KV) + sc8, &Vs[BUF][(w * 8) * 64]);        \
  }

  STAGE(0, 0);

  int buf = 0;
  for (int it = 0; it < NS / 64; ++it) {
    if (it + 1 < NS / 64) {
      STAGE(buf ^ 1, (it + 1) * 64);
      asm volatile("s_waitcnt vmcnt(2)" ::: "memory");
    } else {
      asm volatile("s_waitcnt vmcnt(0)" ::: "memory");
    }
    __builtin_amdgcn_s_barrier();

    f32x4 sv[2][4];
#pragma unroll
    for (int sj = 0; sj < 2; ++sj)
#pragma unroll
      for (int kt = 0; kt < 4; ++kt) sv[sj][kt] = (f32x4){0.f, 0.f, 0.f, 0.f};
    __builtin_amdgcn_s_setprio(1);
#pragma unroll
    for (int kt = 0; kt < 4; ++kt) {
      const char* kr = (const char*)&Ks[buf][(kt * 16 + c) * 64];
      bf16x8 ka0 = *(const bf16x8*)(kr + ((g * 16) ^ swz));
      bf16x8 ka1 = *(const bf16x8*)(kr + ((64 + g * 16) ^ swz));
#pragma unroll
      for (int sj = 0; sj < 2; ++sj) {
        sv[sj][kt] = __builtin_amdgcn_mfma_f32_16x16x32_bf16(ka0, qf[sj][0], sv[sj][kt], 0, 0, 0);
        sv[sj][kt] = __builtin_amdgcn_mfma_f32_16x16x32_bf16(ka1, qf[sj][1], sv[sj][kt], 0, 0, 0);
      }
    }
    __builtin_amdgcn_s_setprio(0);

    float pm[2];
#pragma unroll
    for (int sj = 0; sj < 2; ++sj) {
      float m = -1e30f;
#pragma unroll
      for (int kt = 0; kt < 4; ++kt)
#pragma unroll
        for (int r = 0; r < 4; ++r) {
          sv[sj][kt][r] *= 0.125f;
          m = fmaxf(m, sv[sj][kt][r]);
        }
      m = fmaxf(m, __shfl_xor(m, 16));
      m = fmaxf(m, __shfl_xor(m, 32));
      pm[sj] = m;
    }
    int cond = (pm[0] <= mx[0] + 8.f) && (pm[1] <= mx[1] + 8.f);
    if (!__all(cond)) {
#pragma unroll
      for (int sj = 0; sj < 2; ++sj) {
        float mn = fmaxf(mx[sj], pm[sj]);
        float sc = __expf(mx[sj] - mn);
        mx[sj] = mn;
        lsum[sj] *= sc;
#pragma unroll
        for (int ds = 0; ds < 4; ++ds)
#pragma unroll
          for (int r = 0; r < 4; ++r) o[sj][ds][r] *= sc;
      }
    }
#pragma unroll
    for (int sj = 0; sj < 2; ++sj) {
      float rs = 0.f;
#pragma unroll
      for (int kt = 0; kt < 4; ++kt) {
        bf16x4 pw;
#pragma unroll
        for (int r = 0; r < 4; ++r) {
          float e = __expf(sv[sj][kt][r] - mx[sj]);
          rs += e;
          pw[r] = (bf16)e;
        }
        *(bf16x4*)&Pl[w][sj][c * 68 + kt * 16 + 4 * g] = pw;
      }
      rs += __shfl_xor(rs, 16);
      rs += __shfl_xor(rs, 32);
      lsum[sj] += rs;
    }
    asm volatile("s_waitcnt lgkmcnt(0)" ::: "memory");
    __builtin_amdgcn_sched_barrier(0);

    __builtin_amdgcn_s_setprio(1);
#pragma unroll
    for (int ks = 0; ks < 2; ++ks) {
      bf16x8 pb0 = *(const bf16x8*)&Pl[w][0][c * 68 + ks * 32 + g * 8];
      bf16x8 pb1 = *(const bf16x8*)&Pl[w][1][c * 68 + ks * 32 + g * 8];
#pragma unroll
      for (int ds = 0; ds < 4; ++ds) {
        const char* vr = (const char*)&Vs[buf][(ds * 16 + c) * 64];
        bf16x8 va = *(const bf16x8*)(vr + ((ks * 64 + g * 16) ^ swz));
        o[0][ds] = __builtin_amdgcn_mfma_f32_16x16x32_bf16(va, pb0, o[0][ds], 0, 0, 0);
        o[1][ds] = __builtin_amdgcn_mfma_f32_16x16x32_bf16(va, pb1, o[1][ds], 0, 0, 0);
      }
    }
    __builtin_amdgcn_s_setprio(0);
    __builtin_amdgcn_s_barrier();
    buf ^= 1;
  }

#pragma unroll
  for (int sj = 0; sj < 2; ++sj) {
    float inv = 1.f / lsum[sj];
    bf16* Orow = O + (long)(b * NS + q0 + sj * 16 + c) * ND + h * NDK;
#pragma unroll
    for (int ds = 0; ds < 4; ++ds) {
      bf16x4 ov;
#pragma unroll
      for (int r = 0; r < 4; ++r) ov[r] = (bf16)(o[sj][ds][r] * inv);
      *(bf16x4*)(Orow + ds * 16 + 4 * g) = ov;
    }
  }
#undef STAGE
}

extern "C" void kernel_launch(void* const* d_in, const int* in_sizes, int n_in,
                              void* d_out, int out_size, void* d_ws, size_t ws_size,
                              hipStream_t stream) {
  (void)in_sizes; (void)n_in; (void)out_size; (void)ws_size;
  const float* x = (const float*)d_in[0];
  const float* y = (const float*)d_in[1];
  const float* x_pos = (const float*)d_in[2];
  const float* y_pos = (const float*)d_in[3];

  char* ws = (char*)d_ws;
  const size_t MB = 1ull << 20;
  bf16* Wt[8];
  for (int i = 0; i < 8; ++i) Wt[i] = (bf16*)(ws + (size_t)i * 2 * MB);
  bf16* W1T = (bf16*)(ws + 16 * MB);
  bf16* W2T = (bf16*)(ws + 24 * MB);
  float* xres = (float*)(ws + 32 * MB);
  bf16* x2 = (bf16*)(ws + 64 * MB);
  bf16* qk = (bf16*)(ws + 80 * MB);
  bf16* y2 = (bf16*)(ws + 96 * MB);
  bf16* yk = (bf16*)(ws + 112 * MB);
  bf16* Qb = (bf16*)(ws + 128 * MB);
  bf16* Kb = (bf16*)(ws + 144 * MB);
  bf16* VTb = (bf16*)(ws + 176 * MB);
  bf16* Ob = (bf16*)(ws + 192 * MB);
  bf16* hb = (bf16*)(ws + 128 * MB);  // aliases Qb..VTb (free during FFN)

  dim3 tb(32, 8);
  WPtrs wp;
  for (int i = 0; i < 8; ++i) wp.w[i] = (const float*)d_in[4 + 2 * i];
  wconv8<<<dim3(32, 32, 8), tb, 0, stream>>>(wp, (bf16*)ws);
  wconv_t<<<dim3(128, 32), tb, 0, stream>>>((const float*)d_in[20], W1T, 1024, 4096);
  wconv_t<<<dim3(32, 128), tb, 0, stream>>>((const float*)d_in[22], W2T, 4096, 1024);

  const float* ln1g = (const float*)d_in[24]; const float* ln1b = (const float*)d_in[25];
  const float* ln2g = (const float*)d_in[26]; const float* ln2b = (const float*)d_in[27];
  const float* ln3g = (const float*)d_in[28]; const float* ln3b = (const float*)d_in[29];
  const float* ln4g = (const float*)d_in[30]; const float* ln4b = (const float*)d_in[31];

  dim3 gD(64, 8);      // 128^2 tiles
  dim3 gF1(32, 32);    // 256x128 tiles for FFN1

  // ---- self-attention ----
  ln_fused<<<8192, 256, 0, stream>>>(x, ln1g, ln1b, x_pos, x2, qk);
  gemm_bt<0><<<gD, 256, 0, stream>>>(qk, Wt[0], (const float*)d_in[5], nullptr, Qb, 8192, 1024, 1024);
  gemm_bt<0><<<gD, 256, 0, stream>>>(qk, Wt[1], (const float*)d_in[7], nullptr, Kb, 8192, 1024, 1024);
  gemm_bt<3><<<gD, 256, 0, stream>>>(x2, Wt[2], (const float*)d_in[9], nullptr, VTb, 8192, 1024, 1024);
  attn_fwd<<<512, 512, 0, stream>>>(Qb, Kb, VTb, Ob);
  gemm_bt<1><<<gD, 256, 0, stream>>>(Ob, Wt[3], (const float*)d_in[11], x, xres, 8192, 1024, 1024);

  // ---- cross-attention ----
  ln_fused<<<8192, 256, 0, stream>>>(xres, ln2g, ln2b, x_pos, nullptr, qk);
  ln_fused<<<8192, 256, 0, stream>>>(y, ln3g, ln3b, y_pos, y2, yk);
  gemm_bt<0><<<gD, 256, 0, stream>>>(qk, Wt[4], (const float*)d_in[13], nullptr, Qb, 8192, 1024, 1024);
  gemm_bt<0><<<gD, 256, 0, stream>>>(yk, Wt[5], (const float*)d_in[15], nullptr, Kb, 8192, 1024, 1024);
  gemm_bt<3><<<gD, 256, 0, stream>>>(y2, Wt[6], (const float*)d_in[17], nullptr, VTb, 8192, 1024, 1024);
  attn_fwd<<<512, 512, 0, stream>>>(Qb, Kb, VTb, Ob);
  gemm_bt<1><<<gD, 256, 0, stream>>>(Ob, Wt[7], (const float*)d_in[19], xres, xres, 8192, 1024, 1024);

  // ---- FFN ----
  ln_fused<<<8192, 256, 0, stream>>>(xres, ln4g, ln4b, nullptr, x2, nullptr);
  gemm_bt8<2><<<gF1, 512, 0, stream>>>(x2, W1T, (const float*)d_in[21], nullptr, hb, 8192, 4096, 1024);
  gemm_bt<1><<<gD, 256, 0, stream>>>(hb, W2T, (const float*)d_in[23], xres, (float*)d_out, 8192, 1024, 4096);
}